// Round 15
// baseline (421.509 us; speedup 1.0000x reference)
//
#include <hip/hip_runtime.h>

typedef unsigned short ushort_t;
typedef __attribute__((ext_vector_type(8))) __bf16 bf16x8;
typedef __attribute__((ext_vector_type(4))) float f32x4;
typedef __attribute__((address_space(1))) const void gas_t;
typedef __attribute__((address_space(3))) void las_t;

#define HD 128
#define NL 4
#define SCAN_C 2048   // elements per scan block (256 thr x 8)

__device__ __forceinline__ ushort_t f2bf(float f){
  unsigned u = __builtin_bit_cast(unsigned, f);
  unsigned r = (u + 0x7FFFu + ((u >> 16) & 1u)) >> 16;
  return (ushort_t)r;
}

__device__ __forceinline__ float bf2f(ushort_t u){
  unsigned v = ((unsigned)u) << 16;
  return __builtin_bit_cast(float, v);
}

__device__ __forceinline__ f32x4 mfma16(bf16x8 a, bf16x8 b, f32x4 c){
  return __builtin_amdgcn_mfma_f32_16x16x32_bf16(a, b, c, 0, 0, 0);
}

// ---------------- prep kernels ----------------
__global__ void hist_kernel(const int* __restrict__ dst, int* __restrict__ deg, int E){
  int e = blockIdx.x * 256 + threadIdx.x;
  if (e < E) atomicAdd(&deg[dst[e]], 1);
}

// batch is sorted: goff[g] = first node with batch >= g, goff[G] = N. No atomics.
__global__ void gbound_kernel(const int* __restrict__ batch, int* __restrict__ goff,
                              int N, int G){
  int n = blockIdx.x * 256 + threadIdx.x;
  if (n >= N) return;
  int bc = batch[n];
  int bp = (n == 0) ? -1 : batch[n - 1];
  for (int g = bp + 1; g <= bc; ++g) goff[g] = n;
  if (n == N - 1)
    for (int g = bc + 1; g <= G; ++g) goff[g] = N;
}

// ---- multi-block exclusive scan: part -> top -> final (for node degrees) ----
__global__ void scan_part(const int* __restrict__ in, int* __restrict__ bsum, int n){
  int b = blockIdx.x, tid = threadIdx.x;
  int base = b * SCAN_C + tid * 8;
  int s = 0;
  if (base + 8 <= n){
    int4 a = *(const int4*)(in + base);
    int4 c = *(const int4*)(in + base + 4);
    s = a.x + a.y + a.z + a.w + c.x + c.y + c.z + c.w;
  } else {
    #pragma unroll
    for (int k = 0; k < 8; ++k) if (base + k < n) s += in[base + k];
  }
  #pragma unroll
  for (int o = 1; o < 64; o <<= 1) s += __shfl_xor(s, o, 64);
  __shared__ int ws[4];
  int lane = tid & 63, wid = tid >> 6;
  if (lane == 0) ws[wid] = s;
  __syncthreads();
  if (tid == 0) bsum[b] = ws[0] + ws[1] + ws[2] + ws[3];
}

// 1 block, 256 threads; B <= 256. Writes exclusive offsets + grand total to *outn.
__global__ void scan_top(const int* __restrict__ bsum, int* __restrict__ bofs,
                         int* __restrict__ outn, int B){
  int tid = threadIdx.x;
  int v = (tid < B) ? bsum[tid] : 0;
  int lane = tid & 63, wid = tid >> 6;
  int inc = v;
  #pragma unroll
  for (int o = 1; o < 64; o <<= 1){
    int t = __shfl_up(inc, o, 64);
    if (lane >= o) inc += t;
  }
  __shared__ int ws[4];
  if (lane == 63) ws[wid] = inc;
  __syncthreads();
  int wprev = 0;
  for (int i = 0; i < wid; ++i) wprev += ws[i];
  if (tid < B) bofs[tid] = inc - v + wprev;
  if (tid == 0) *outn = ws[0] + ws[1] + ws[2] + ws[3];
}

__global__ void scan_final(const int* __restrict__ in, const int* __restrict__ bofs,
                           int* __restrict__ out, int* __restrict__ cur, int n){
  int b = blockIdx.x, tid = threadIdx.x;
  int base = b * SCAN_C + tid * 8;
  int v[8];
  if (base + 8 <= n){
    *(int4*)(v)     = *(const int4*)(in + base);
    *(int4*)(v + 4) = *(const int4*)(in + base + 4);
  } else {
    #pragma unroll
    for (int k = 0; k < 8; ++k) v[k] = (base + k < n) ? in[base + k] : 0;
  }
  int tsum = 0;
  #pragma unroll
  for (int k = 0; k < 8; ++k) tsum += v[k];
  int lane = tid & 63, wid = tid >> 6;
  int inc = tsum;
  #pragma unroll
  for (int o = 1; o < 64; o <<= 1){
    int t = __shfl_up(inc, o, 64);
    if (lane >= o) inc += t;
  }
  __shared__ int ws[4];
  if (lane == 63) ws[wid] = inc;
  __syncthreads();
  int run = bofs[b] + inc - tsum;
  for (int i = 0; i < wid; ++i) run += ws[i];
  #pragma unroll
  for (int k = 0; k < 8; ++k){
    int i = base + k;
    if (i < n){
      out[i] = run;
      if (cur) cur[i] = run;
      run += v[k];
    }
  }
}

// slim CSR scatter: 4B payload per edge (perm[p] = edge id)
__global__ void scatter_kernel(const int* __restrict__ dst, int* __restrict__ cursor,
                               int* __restrict__ perm, int E){
  int e = blockIdx.x * 256 + threadIdx.x;
  if (e < E){
    int d = dst[e];
    int p = atomicAdd(&cursor[d], 1);
    perm[p] = e;
  }
}

// coalesced permute: sequential writes, gathered reads (src 2.5MB, eattr 10MB: L2-able)
__global__ void permute_kernel(const int* __restrict__ perm, const int* __restrict__ src,
                               const float4* __restrict__ ea, int* __restrict__ srcs_s,
                               float4* __restrict__ ea4p, int E){
  int p = blockIdx.x * 256 + threadIdx.x;
  if (p < E){
    int e = perm[p];
    srcs_s[p] = src[e];
    ea4p[p] = ea[e];
  }
}

// W1 [L][128][256] -> W1t bf16 [L][256][128]; W2 [L][256][128] -> W2t bf16 [L][128][256]
__global__ void wconv_kernel(const float* __restrict__ W1, const float* __restrict__ W2,
                             ushort_t* __restrict__ W1t, ushort_t* __restrict__ W2t){
  int i = blockIdx.x * 256 + threadIdx.x;
  if (i < NL * 32768){
    int l = i >> 15, r = i & 32767;
    int n = r >> 7, k = r & 127;                 // W1t[l][n][k], n<256, k<128
    W1t[i] = f2bf(W1[l * 32768 + k * 256 + n]);
  } else {
    int i2 = i - NL * 32768;
    int l = i2 >> 15, r = i2 & 32767;
    int n = r >> 8, k = r & 255;                 // W2t[l][n][k], n<128, k<256
    W2t[i2] = f2bf(W2[l * 32768 + k * 128 + n]);
  }
}

// ---------------- encoder ----------------
__global__ void encoder_kernel(const float* __restrict__ x, const float* __restrict__ Wn,
                               const float* __restrict__ bn, float* __restrict__ h,
                               ushort_t* __restrict__ hb, int N){
  int n = blockIdx.x, j = threadIdx.x;
  float acc = bn[j];
  #pragma unroll
  for (int k = 0; k < 9; ++k) acc = fmaf(x[n * 9 + k], Wn[k * HD + j], acc);
  h[(size_t)n * HD + j] = acc;
  hb[(size_t)n * HD + j] = f2bf(acc);
}

// ------- message + aggregate:  z = bf16(h + sum_in relu(hb[src] + ea)) -------
// grid-stride persistent blocks (128 thr): We/be setup loaded once per block,
// then the proven 8-deep gather-pipeline body per node. ~16 nodes/block at
// grid=3072 (~12 blocks/CU resident, same TLP as the block-per-node version).
__global__ void agg_kernel(const float* __restrict__ h, const ushort_t* __restrict__ hb,
                           const int* __restrict__ off, const int* __restrict__ srcs,
                           const float4* __restrict__ ea4, const float* __restrict__ We,
                           const float* __restrict__ be, ushort_t* __restrict__ z,
                           int N, int nblocks){
  int j = threadIdx.x;
  float w0 = We[j], w1 = We[HD + j], w2 = We[2 * HD + j], w3 = We[3 * HD + j];
  float bj = be[j];
  for (int n = blockIdx.x; n < N; n += nblocks){
    int s = off[n], e = off[n + 1];
    float acc = h[(size_t)n * HD + j];
    int i = s;
    for (; i + 8 <= e; i += 8){
      int s0 = srcs[i],     s1 = srcs[i + 1], s2 = srcs[i + 2], s3 = srcs[i + 3];
      int s4 = srcs[i + 4], s5 = srcs[i + 5], s6 = srcs[i + 6], s7 = srcs[i + 7];
      ushort_t g0 = hb[(size_t)s0 * HD + j];
      ushort_t g1 = hb[(size_t)s1 * HD + j];
      ushort_t g2 = hb[(size_t)s2 * HD + j];
      ushort_t g3 = hb[(size_t)s3 * HD + j];
      ushort_t g4 = hb[(size_t)s4 * HD + j];
      ushort_t g5 = hb[(size_t)s5 * HD + j];
      ushort_t g6 = hb[(size_t)s6 * HD + j];
      ushort_t g7 = hb[(size_t)s7 * HD + j];
      {
        float4 a0 = ea4[i], a1 = ea4[i + 1], a2 = ea4[i + 2], a3 = ea4[i + 3];
        float e0 = fmaf(a0.x, w0, fmaf(a0.y, w1, fmaf(a0.z, w2, fmaf(a0.w, w3, bj))));
        float e1 = fmaf(a1.x, w0, fmaf(a1.y, w1, fmaf(a1.z, w2, fmaf(a1.w, w3, bj))));
        float e2 = fmaf(a2.x, w0, fmaf(a2.y, w1, fmaf(a2.z, w2, fmaf(a2.w, w3, bj))));
        float e3 = fmaf(a3.x, w0, fmaf(a3.y, w1, fmaf(a3.z, w2, fmaf(a3.w, w3, bj))));
        acc += fmaxf(bf2f(g0) + e0, 0.f);
        acc += fmaxf(bf2f(g1) + e1, 0.f);
        acc += fmaxf(bf2f(g2) + e2, 0.f);
        acc += fmaxf(bf2f(g3) + e3, 0.f);
      }
      {
        float4 a4 = ea4[i + 4], a5 = ea4[i + 5], a6 = ea4[i + 6], a7 = ea4[i + 7];
        float e4 = fmaf(a4.x, w0, fmaf(a4.y, w1, fmaf(a4.z, w2, fmaf(a4.w, w3, bj))));
        float e5 = fmaf(a5.x, w0, fmaf(a5.y, w1, fmaf(a5.z, w2, fmaf(a5.w, w3, bj))));
        float e6 = fmaf(a6.x, w0, fmaf(a6.y, w1, fmaf(a6.z, w2, fmaf(a6.w, w3, bj))));
        float e7 = fmaf(a7.x, w0, fmaf(a7.y, w1, fmaf(a7.z, w2, fmaf(a7.w, w3, bj))));
        acc += fmaxf(bf2f(g4) + e4, 0.f);
        acc += fmaxf(bf2f(g5) + e5, 0.f);
        acc += fmaxf(bf2f(g6) + e6, 0.f);
        acc += fmaxf(bf2f(g7) + e7, 0.f);
      }
    }
    for (; i + 4 <= e; i += 4){
      int s0 = srcs[i], s1 = srcs[i + 1], s2 = srcs[i + 2], s3 = srcs[i + 3];
      float4 a0 = ea4[i], a1 = ea4[i + 1], a2 = ea4[i + 2], a3 = ea4[i + 3];
      float h0 = bf2f(hb[(size_t)s0 * HD + j]);
      float h1 = bf2f(hb[(size_t)s1 * HD + j]);
      float h2 = bf2f(hb[(size_t)s2 * HD + j]);
      float h3 = bf2f(hb[(size_t)s3 * HD + j]);
      float e0 = fmaf(a0.x, w0, fmaf(a0.y, w1, fmaf(a0.z, w2, fmaf(a0.w, w3, bj))));
      float e1 = fmaf(a1.x, w0, fmaf(a1.y, w1, fmaf(a1.z, w2, fmaf(a1.w, w3, bj))));
      float e2 = fmaf(a2.x, w0, fmaf(a2.y, w1, fmaf(a2.z, w2, fmaf(a2.w, w3, bj))));
      float e3 = fmaf(a3.x, w0, fmaf(a3.y, w1, fmaf(a3.z, w2, fmaf(a3.w, w3, bj))));
      acc += fmaxf(h0 + e0, 0.f);
      acc += fmaxf(h1 + e1, 0.f);
      acc += fmaxf(h2 + e2, 0.f);
      acc += fmaxf(h3 + e3, 0.f);
    }
    for (; i < e; ++i){
      int sc = srcs[i];
      float4 a = ea4[i];
      float eav = fmaf(a.x, w0, fmaf(a.y, w1, fmaf(a.z, w2, fmaf(a.w, w3, bj))));
      acc += fmaxf(bf2f(hb[(size_t)sc * HD + j]) + eav, 0.f);
    }
    z[(size_t)n * HD + j] = f2bf(acc);
  }
}

// ------- fused MLP (R12 structure; z-staging via global_load_lds width=16) -------
// t = relu(z@W1+b1) in LDS; z2 = t@W2+b2; LN+relu+residual.
// 512 thr, LDS = 64KB -> 2 blocks/CU. LDS dest is LINEAR (lane x 16B); the XOR
// swizzle is applied to the GLOBAL source chunk index (m173 pattern), so the
// phase-1 swizzled reads are unchanged.
__global__ __launch_bounds__(512, 4) void mlp_fused_kernel(
    const ushort_t* __restrict__ zin, const ushort_t* __restrict__ W1t,
    const float* __restrict__ b1, const ushort_t* __restrict__ W2t,
    const float* __restrict__ b2, const float* __restrict__ gamma,
    const float* __restrict__ beta, float* __restrict__ h,
    ushort_t* __restrict__ hb, int N){
  extern __shared__ char lds[];   // [0,32K): z tile; then [0,64K): t tile; [0,4K): stats
  int tid = threadIdx.x;
  int r0 = blockIdx.x * 128;
  // ---- stage z tile [128 node][128 k] bf16 via async global->LDS ----
  // linear LDS slot g*16 <- z[row][ (kg ^ (row&7)) * 8 .. +8 ]
  #pragma unroll
  for (int i = 0; i < 4; ++i){
    int g = i * 512 + tid;
    int row = g >> 4, kg = g & 15;
    int ar = min(r0 + row, N - 1);
    const ushort_t* gp = zin + (size_t)ar * 128 + (kg ^ (row & 7)) * 8;
    __builtin_amdgcn_global_load_lds((gas_t*)gp, (las_t*)(lds + g * 16), 16, 0, 0);
  }
  int w = tid >> 6, l = tid & 63;
  int lr = l & 15, lk = l >> 4;
  int wk = w >> 1, wn = w & 1;
  // prefetch phase-1 ks=0 weight fragments BEFORE the staging barrier
  bf16x8 aN[4];
  #pragma unroll
  for (int fm = 0; fm < 4; ++fm)
    aN[fm] = *(const bf16x8*)((const char*)W1t +
              (size_t)(wk * 64 + fm * 16 + lr) * 256 + lk * 16);
  __syncthreads();                                  // bar1: z staged (drains vmcnt)
  // ---- phase 1: wave grid wk(4) x wn(2); each wave 64 k2 x 64 node ----
  {
    f32x4 acc1[4][4] = {};
    #pragma unroll
    for (int ks = 0; ks < 4; ++ks){
      int kb = ks * 64 + lk * 16;                   // byte offset in 256B z-row
      bf16x8 aC[4];
      #pragma unroll
      for (int fm = 0; fm < 4; ++fm) aC[fm] = aN[fm];
      if (ks < 3){
        int kbn = (ks + 1) * 64 + lk * 16;
        #pragma unroll
        for (int fm = 0; fm < 4; ++fm)
          aN[fm] = *(const bf16x8*)((const char*)W1t +
                    (size_t)(wk * 64 + fm * 16 + lr) * 256 + kbn);
      }
      bf16x8 b[4];
      #pragma unroll
      for (int fn = 0; fn < 4; ++fn){
        int node = wn * 64 + fn * 16 + lr;
        b[fn] = *(const bf16x8*)(lds + node * 256 + (kb ^ ((node & 7) << 4)));
      }
      #pragma unroll
      for (int fm = 0; fm < 4; ++fm)
        #pragma unroll
        for (int fn = 0; fn < 4; ++fn)
          acc1[fm][fn] = mfma16(aC[fm], b[fn], acc1[fm][fn]);
    }
    __syncthreads();                                // bar2: z reads done, overwrite with t
    // bias + relu + write t[node][k2] bf16 (swizzled, row stride 512B)
    #pragma unroll
    for (int fm = 0; fm < 4; ++fm){
      f32x4 bv = *(const f32x4*)(b1 + wk * 64 + fm * 16 + lk * 4);
      int k2b = (wk * 64 + fm * 16 + lk * 4) * 2;   // byte offset in 512B t-row
      #pragma unroll
      for (int fn = 0; fn < 4; ++fn){
        int node = wn * 64 + fn * 16 + lr;
        ushort4 tv;
        tv.x = f2bf(fmaxf(acc1[fm][fn][0] + bv[0], 0.f));
        tv.y = f2bf(fmaxf(acc1[fm][fn][1] + bv[1], 0.f));
        tv.z = f2bf(fmaxf(acc1[fm][fn][2] + bv[2], 0.f));
        tv.w = f2bf(fmaxf(acc1[fm][fn][3] + bv[3], 0.f));
        *(ushort4*)(lds + node * 512 + (k2b ^ ((node & 7) << 4))) = tv;
      }
    }
  }
  // prefetch phase-2 ks=0 weight fragments BEFORE the t barrier
  int wd = w >> 1, wn2 = w & 1;
  bf16x8 a2N[2];
  #pragma unroll
  for (int fm = 0; fm < 2; ++fm)
    a2N[fm] = *(const bf16x8*)((const char*)W2t +
               (size_t)(wd * 32 + fm * 16 + lr) * 512 + lk * 16);
  __syncthreads();                                  // bar3: t fully written
  // ---- phase 2: wave grid wd(4) x wn2(2); each wave 32 d x 64 node ----
  f32x4 acc2[2][4] = {};
  #pragma unroll
  for (int ks = 0; ks < 8; ++ks){
    int kb = ks * 64 + lk * 16;                     // byte offset in 512B t-row
    bf16x8 a2C[2];
    #pragma unroll
    for (int fm = 0; fm < 2; ++fm) a2C[fm] = a2N[fm];
    if (ks < 7){
      int kbn = (ks + 1) * 64 + lk * 16;
      #pragma unroll
      for (int fm = 0; fm < 2; ++fm)
        a2N[fm] = *(const bf16x8*)((const char*)W2t +
                   (size_t)(wd * 32 + fm * 16 + lr) * 512 + kbn);
    }
    bf16x8 bt2[4];
    #pragma unroll
    for (int fn = 0; fn < 4; ++fn){
      int node = wn2 * 64 + fn * 16 + lr;
      bt2[fn] = *(const bf16x8*)(lds + node * 512 + (kb ^ ((node & 7) << 4)));
    }
    #pragma unroll
    for (int fm = 0; fm < 2; ++fm)
      #pragma unroll
      for (int fn = 0; fn < 4; ++fn)
        acc2[fm][fn] = mfma16(a2C[fm], bt2[fn], acc2[fm][fn]);
  }
  __syncthreads();                                  // bar4: t reads done, stat region free
  float* stat_s = (float*)lds;                      // [128 node][4 wd]
  float* stat_q = (float*)(lds + 2048);
  f32x4 b2v[2], gv[2], btv[2];
  #pragma unroll
  for (int fm = 0; fm < 2; ++fm){
    int db = wd * 32 + fm * 16 + lk * 4;
    b2v[fm] = *(const f32x4*)(b2 + db);
    gv[fm]  = *(const f32x4*)(gamma + db);
    btv[fm] = *(const f32x4*)(beta + db);
  }
  #pragma unroll
  for (int fn = 0; fn < 4; ++fn){
    float ss = 0.f, qq = 0.f;
    #pragma unroll
    for (int fm = 0; fm < 2; ++fm)
      #pragma unroll
      for (int r = 0; r < 4; ++r){
        float v = acc2[fm][fn][r] + b2v[fm][r];
        acc2[fm][fn][r] = v;
        ss += v; qq += v * v;
      }
    ss += __shfl_xor(ss, 16, 64); ss += __shfl_xor(ss, 32, 64);
    qq += __shfl_xor(qq, 16, 64); qq += __shfl_xor(qq, 32, 64);
    if (l < 16){
      int node = wn2 * 64 + fn * 16 + lr;
      stat_s[node * 4 + wd] = ss;
      stat_q[node * 4 + wd] = qq;
    }
  }
  __syncthreads();                                  // bar5: stats ready
  #pragma unroll
  for (int fn = 0; fn < 4; ++fn){
    int node = wn2 * 64 + fn * 16 + lr;
    int gn = r0 + node;
    float ss = stat_s[node * 4 + 0] + stat_s[node * 4 + 1] +
               stat_s[node * 4 + 2] + stat_s[node * 4 + 3];
    float qq = stat_q[node * 4 + 0] + stat_q[node * 4 + 1] +
               stat_q[node * 4 + 2] + stat_q[node * 4 + 3];
    float mean = ss * (1.f / 128.f);
    float rs = rsqrtf(qq * (1.f / 128.f) - mean * mean + 1e-5f);
    if (gn < N){
      #pragma unroll
      for (int fm = 0; fm < 2; ++fm){
        int db = wd * 32 + fm * 16 + lk * 4;
        f32x4 hold = *(const f32x4*)(h + (size_t)gn * HD + db);
        f32x4 ov;
        #pragma unroll
        for (int r = 0; r < 4; ++r)
          ov[r] = fmaxf((acc2[fm][fn][r] - mean) * rs * gv[fm][r] + btv[fm][r], 0.f) + hold[r];
        *(f32x4*)(h + (size_t)gn * HD + db) = ov;
        ushort4 hv;
        hv.x = f2bf(ov[0]); hv.y = f2bf(ov[1]); hv.z = f2bf(ov[2]); hv.w = f2bf(ov[3]);
        *(ushort4*)(hb + (size_t)gn * HD + db) = hv;
      }
    }
  }
}

// ---------------- pool (batch is sorted -> contiguous node ranges) ----------------
__global__ void pool_kernel(const float* __restrict__ h, const int* __restrict__ goff,
                            float* __restrict__ outp, int G){
  int g = blockIdx.x, j = threadIdx.x;
  int s = goff[g], e = goff[g + 1];
  float acc = 0.f;
  for (int i = s; i < e; ++i) acc += h[(size_t)i * HD + j];
  outp[(size_t)g * HD + j] = acc;
}

extern "C" void kernel_launch(void* const* d_in, const int* in_sizes, int n_in,
                              void* d_out, int out_size, void* d_ws, size_t ws_size,
                              hipStream_t stream){
  const float* x     = (const float*)d_in[0];
  const int*   ei    = (const int*)  d_in[1];
  const float* eattr = (const float*)d_in[2];
  const int*   batch = (const int*)  d_in[3];
  const float* Wn    = (const float*)d_in[4];
  const float* bn    = (const float*)d_in[5];
  const float* We    = (const float*)d_in[6];
  const float* be    = (const float*)d_in[7];
  const float* W1    = (const float*)d_in[8];
  const float* b1    = (const float*)d_in[9];
  const float* W2    = (const float*)d_in[10];
  const float* b2    = (const float*)d_in[11];
  const float* gamma = (const float*)d_in[12];
  const float* beta  = (const float*)d_in[13];
  float* outp = (float*)d_out;

  int N = in_sizes[3];
  int E = in_sizes[2] / 4;
  int G = out_size / HD;

  char* base = (char*)d_ws;
  size_t o = 0;
  auto alloc = [&](size_t bytes)->char*{
    char* r = base + o; o = (o + bytes + 255) & ~(size_t)255; return r;
  };
  float*    h    = (float*)   alloc((size_t)N * HD * 4);
  ushort_t* hb   = (ushort_t*)alloc((size_t)N * HD * 2);
  ushort_t* z    = (ushort_t*)alloc((size_t)N * HD * 2);
  ushort_t* W1t  = (ushort_t*)alloc((size_t)NL * 2 * HD * HD * 2);
  ushort_t* W2t  = (ushort_t*)alloc((size_t)NL * 2 * HD * HD * 2);
  int* deg    = (int*)alloc((size_t)N * 4);
  int* off    = (int*)alloc((size_t)(N + 1) * 4);
  int* goff   = (int*)alloc((size_t)(G + 1) * 4);
  int* cursor = (int*)alloc((size_t)N * 4);
  int* bsumN  = (int*)alloc(512 * 4);
  int* bofsN  = (int*)alloc(512 * 4);
  int* perm   = (int*)alloc((size_t)E * 4);
  int* srcs_s = (int*)alloc((size_t)E * 4);
  float4* ea4p= (float4*)alloc((size_t)E * 16);
  (void)ws_size; (void)n_in;

  const int* src = ei;
  const int* dst = ei + E;

  hipMemsetAsync(deg, 0, (size_t)N * 4, stream);

  hist_kernel<<<(E + 255) / 256, 256, 0, stream>>>(dst, deg, E);
  gbound_kernel<<<(N + 255) / 256, 256, 0, stream>>>(batch, goff, N, G);

  int BN = (N + SCAN_C - 1) / SCAN_C;
  scan_part<<<BN, 256, 0, stream>>>(deg, bsumN, N);
  scan_top<<<1, 256, 0, stream>>>(bsumN, bofsN, off + N, BN);
  scan_final<<<BN, 256, 0, stream>>>(deg, bofsN, off, cursor, N);

  scatter_kernel<<<(E + 255) / 256, 256, 0, stream>>>(dst, cursor, perm, E);
  permute_kernel<<<(E + 255) / 256, 256, 0, stream>>>(perm, src, (const float4*)eattr,
                                                      srcs_s, ea4p, E);
  wconv_kernel<<<(2 * NL * 32768) / 256, 256, 0, stream>>>(W1, W2, W1t, W2t);
  encoder_kernel<<<N, HD, 0, stream>>>(x, Wn, bn, h, hb, N);

  int ablocks = 3072;
  if (ablocks > N) ablocks = N;
  int mblocks = (N + 127) / 128;
  for (int l = 0; l < NL; ++l){
    agg_kernel<<<ablocks, HD, 0, stream>>>(h, hb, off, srcs_s, ea4p, We, be, z, N, ablocks);
    mlp_fused_kernel<<<mblocks, 512, 65536, stream>>>(
        z, W1t + (size_t)l * 2 * HD * HD, b1 + l * 2 * HD,
        W2t + (size_t)l * 2 * HD * HD, b2 + l * HD,
        gamma + l * HD, beta + l * HD, h, hb, N);
  }
  pool_kernel<<<G, HD, 0, stream>>>(h, goff, outp, G);
}

// Round 16
// 397.619 us; speedup vs baseline: 1.0601x; 1.0601x over previous
//
#include <hip/hip_runtime.h>

typedef unsigned short ushort_t;
typedef __attribute__((ext_vector_type(8))) __bf16 bf16x8;
typedef __attribute__((ext_vector_type(4))) float f32x4;
typedef __attribute__((address_space(1))) const void gas_t;
typedef __attribute__((address_space(3))) void las_t;

#define HD 128
#define NL 4
#define SCAN_C 2048   // elements per scan block (256 thr x 8)

__device__ __forceinline__ ushort_t f2bf(float f){
  unsigned u = __builtin_bit_cast(unsigned, f);
  unsigned r = (u + 0x7FFFu + ((u >> 16) & 1u)) >> 16;
  return (ushort_t)r;
}

__device__ __forceinline__ float bf2f(ushort_t u){
  unsigned v = ((unsigned)u) << 16;
  return __builtin_bit_cast(float, v);
}

__device__ __forceinline__ f32x4 mfma16(bf16x8 a, bf16x8 b, f32x4 c){
  return __builtin_amdgcn_mfma_f32_16x16x32_bf16(a, b, c, 0, 0, 0);
}

// ---------------- prep kernels ----------------
__global__ void hist_kernel(const int* __restrict__ dst, int* __restrict__ deg, int E){
  int e = blockIdx.x * 256 + threadIdx.x;
  if (e < E) atomicAdd(&deg[dst[e]], 1);
}

// batch is sorted: goff[g] = first node with batch >= g, goff[G] = N. No atomics.
__global__ void gbound_kernel(const int* __restrict__ batch, int* __restrict__ goff,
                              int N, int G){
  int n = blockIdx.x * 256 + threadIdx.x;
  if (n >= N) return;
  int bc = batch[n];
  int bp = (n == 0) ? -1 : batch[n - 1];
  for (int g = bp + 1; g <= bc; ++g) goff[g] = n;
  if (n == N - 1)
    for (int g = bc + 1; g <= G; ++g) goff[g] = N;
}

// ---- multi-block exclusive scan: part -> top -> final (for node degrees) ----
__global__ void scan_part(const int* __restrict__ in, int* __restrict__ bsum, int n){
  int b = blockIdx.x, tid = threadIdx.x;
  int base = b * SCAN_C + tid * 8;
  int s = 0;
  if (base + 8 <= n){
    int4 a = *(const int4*)(in + base);
    int4 c = *(const int4*)(in + base + 4);
    s = a.x + a.y + a.z + a.w + c.x + c.y + c.z + c.w;
  } else {
    #pragma unroll
    for (int k = 0; k < 8; ++k) if (base + k < n) s += in[base + k];
  }
  #pragma unroll
  for (int o = 1; o < 64; o <<= 1) s += __shfl_xor(s, o, 64);
  __shared__ int ws[4];
  int lane = tid & 63, wid = tid >> 6;
  if (lane == 0) ws[wid] = s;
  __syncthreads();
  if (tid == 0) bsum[b] = ws[0] + ws[1] + ws[2] + ws[3];
}

// 1 block, 256 threads; B <= 256. Writes exclusive offsets + grand total to *outn.
__global__ void scan_top(const int* __restrict__ bsum, int* __restrict__ bofs,
                         int* __restrict__ outn, int B){
  int tid = threadIdx.x;
  int v = (tid < B) ? bsum[tid] : 0;
  int lane = tid & 63, wid = tid >> 6;
  int inc = v;
  #pragma unroll
  for (int o = 1; o < 64; o <<= 1){
    int t = __shfl_up(inc, o, 64);
    if (lane >= o) inc += t;
  }
  __shared__ int ws[4];
  if (lane == 63) ws[wid] = inc;
  __syncthreads();
  int wprev = 0;
  for (int i = 0; i < wid; ++i) wprev += ws[i];
  if (tid < B) bofs[tid] = inc - v + wprev;
  if (tid == 0) *outn = ws[0] + ws[1] + ws[2] + ws[3];
}

__global__ void scan_final(const int* __restrict__ in, const int* __restrict__ bofs,
                           int* __restrict__ out, int* __restrict__ cur, int n){
  int b = blockIdx.x, tid = threadIdx.x;
  int base = b * SCAN_C + tid * 8;
  int v[8];
  if (base + 8 <= n){
    *(int4*)(v)     = *(const int4*)(in + base);
    *(int4*)(v + 4) = *(const int4*)(in + base + 4);
  } else {
    #pragma unroll
    for (int k = 0; k < 8; ++k) v[k] = (base + k < n) ? in[base + k] : 0;
  }
  int tsum = 0;
  #pragma unroll
  for (int k = 0; k < 8; ++k) tsum += v[k];
  int lane = tid & 63, wid = tid >> 6;
  int inc = tsum;
  #pragma unroll
  for (int o = 1; o < 64; o <<= 1){
    int t = __shfl_up(inc, o, 64);
    if (lane >= o) inc += t;
  }
  __shared__ int ws[4];
  if (lane == 63) ws[wid] = inc;
  __syncthreads();
  int run = bofs[b] + inc - tsum;
  for (int i = 0; i < wid; ++i) run += ws[i];
  #pragma unroll
  for (int k = 0; k < 8; ++k){
    int i = base + k;
    if (i < n){
      out[i] = run;
      if (cur) cur[i] = run;
      run += v[k];
    }
  }
}

// slim CSR scatter: 4B payload per edge (perm[p] = edge id)
__global__ void scatter_kernel(const int* __restrict__ dst, int* __restrict__ cursor,
                               int* __restrict__ perm, int E){
  int e = blockIdx.x * 256 + threadIdx.x;
  if (e < E){
    int d = dst[e];
    int p = atomicAdd(&cursor[d], 1);
    perm[p] = e;
  }
}

// coalesced permute: sequential writes, gathered reads (src 2.5MB, eattr 10MB: L2-able)
__global__ void permute_kernel(const int* __restrict__ perm, const int* __restrict__ src,
                               const float4* __restrict__ ea, int* __restrict__ srcs_s,
                               float4* __restrict__ ea4p, int E){
  int p = blockIdx.x * 256 + threadIdx.x;
  if (p < E){
    int e = perm[p];
    srcs_s[p] = src[e];
    ea4p[p] = ea[e];
  }
}

// W1 [L][128][256] -> W1t bf16 [L][256][128]; W2 [L][256][128] -> W2t bf16 [L][128][256]
__global__ void wconv_kernel(const float* __restrict__ W1, const float* __restrict__ W2,
                             ushort_t* __restrict__ W1t, ushort_t* __restrict__ W2t){
  int i = blockIdx.x * 256 + threadIdx.x;
  if (i < NL * 32768){
    int l = i >> 15, r = i & 32767;
    int n = r >> 7, k = r & 127;                 // W1t[l][n][k], n<256, k<128
    W1t[i] = f2bf(W1[l * 32768 + k * 256 + n]);
  } else {
    int i2 = i - NL * 32768;
    int l = i2 >> 15, r = i2 & 32767;
    int n = r >> 8, k = r & 255;                 // W2t[l][n][k], n<128, k<256
    W2t[i2] = f2bf(W2[l * 32768 + k * 128 + n]);
  }
}

// ---------------- encoder ----------------
__global__ void encoder_kernel(const float* __restrict__ x, const float* __restrict__ Wn,
                               const float* __restrict__ bn, float* __restrict__ h,
                               ushort_t* __restrict__ hb, int N){
  int n = blockIdx.x, j = threadIdx.x;
  float acc = bn[j];
  #pragma unroll
  for (int k = 0; k < 9; ++k) acc = fmaf(x[n * 9 + k], Wn[k * HD + j], acc);
  h[(size_t)n * HD + j] = acc;
  hb[(size_t)n * HD + j] = f2bf(acc);
}

// ------- message + aggregate:  z = bf16(h + sum_in relu(hb[src] + ea)) -------
// block-per-node (128 thr). 8-deep gather pipeline: all 8 src reads + 8 hb
// gathers issued up front (2B/lane each -> 8 VGPRs), ea4 consumed in 2 groups.
__global__ void agg_kernel(const float* __restrict__ h, const ushort_t* __restrict__ hb,
                           const int* __restrict__ off, const int* __restrict__ srcs,
                           const float4* __restrict__ ea4, const float* __restrict__ We,
                           const float* __restrict__ be, ushort_t* __restrict__ z, int N){
  int n = blockIdx.x, j = threadIdx.x;
  float w0 = We[j], w1 = We[HD + j], w2 = We[2 * HD + j], w3 = We[3 * HD + j];
  float bj = be[j];
  int s = off[n], e = off[n + 1];
  float acc = h[(size_t)n * HD + j];
  int i = s;
  for (; i + 8 <= e; i += 8){
    int s0 = srcs[i],     s1 = srcs[i + 1], s2 = srcs[i + 2], s3 = srcs[i + 3];
    int s4 = srcs[i + 4], s5 = srcs[i + 5], s6 = srcs[i + 6], s7 = srcs[i + 7];
    ushort_t g0 = hb[(size_t)s0 * HD + j];
    ushort_t g1 = hb[(size_t)s1 * HD + j];
    ushort_t g2 = hb[(size_t)s2 * HD + j];
    ushort_t g3 = hb[(size_t)s3 * HD + j];
    ushort_t g4 = hb[(size_t)s4 * HD + j];
    ushort_t g5 = hb[(size_t)s5 * HD + j];
    ushort_t g6 = hb[(size_t)s6 * HD + j];
    ushort_t g7 = hb[(size_t)s7 * HD + j];
    {
      float4 a0 = ea4[i], a1 = ea4[i + 1], a2 = ea4[i + 2], a3 = ea4[i + 3];
      float e0 = fmaf(a0.x, w0, fmaf(a0.y, w1, fmaf(a0.z, w2, fmaf(a0.w, w3, bj))));
      float e1 = fmaf(a1.x, w0, fmaf(a1.y, w1, fmaf(a1.z, w2, fmaf(a1.w, w3, bj))));
      float e2 = fmaf(a2.x, w0, fmaf(a2.y, w1, fmaf(a2.z, w2, fmaf(a2.w, w3, bj))));
      float e3 = fmaf(a3.x, w0, fmaf(a3.y, w1, fmaf(a3.z, w2, fmaf(a3.w, w3, bj))));
      acc += fmaxf(bf2f(g0) + e0, 0.f);
      acc += fmaxf(bf2f(g1) + e1, 0.f);
      acc += fmaxf(bf2f(g2) + e2, 0.f);
      acc += fmaxf(bf2f(g3) + e3, 0.f);
    }
    {
      float4 a4 = ea4[i + 4], a5 = ea4[i + 5], a6 = ea4[i + 6], a7 = ea4[i + 7];
      float e4 = fmaf(a4.x, w0, fmaf(a4.y, w1, fmaf(a4.z, w2, fmaf(a4.w, w3, bj))));
      float e5 = fmaf(a5.x, w0, fmaf(a5.y, w1, fmaf(a5.z, w2, fmaf(a5.w, w3, bj))));
      float e6 = fmaf(a6.x, w0, fmaf(a6.y, w1, fmaf(a6.z, w2, fmaf(a6.w, w3, bj))));
      float e7 = fmaf(a7.x, w0, fmaf(a7.y, w1, fmaf(a7.z, w2, fmaf(a7.w, w3, bj))));
      acc += fmaxf(bf2f(g4) + e4, 0.f);
      acc += fmaxf(bf2f(g5) + e5, 0.f);
      acc += fmaxf(bf2f(g6) + e6, 0.f);
      acc += fmaxf(bf2f(g7) + e7, 0.f);
    }
  }
  for (; i + 4 <= e; i += 4){
    int s0 = srcs[i], s1 = srcs[i + 1], s2 = srcs[i + 2], s3 = srcs[i + 3];
    float4 a0 = ea4[i], a1 = ea4[i + 1], a2 = ea4[i + 2], a3 = ea4[i + 3];
    float h0 = bf2f(hb[(size_t)s0 * HD + j]);
    float h1 = bf2f(hb[(size_t)s1 * HD + j]);
    float h2 = bf2f(hb[(size_t)s2 * HD + j]);
    float h3 = bf2f(hb[(size_t)s3 * HD + j]);
    float e0 = fmaf(a0.x, w0, fmaf(a0.y, w1, fmaf(a0.z, w2, fmaf(a0.w, w3, bj))));
    float e1 = fmaf(a1.x, w0, fmaf(a1.y, w1, fmaf(a1.z, w2, fmaf(a1.w, w3, bj))));
    float e2 = fmaf(a2.x, w0, fmaf(a2.y, w1, fmaf(a2.z, w2, fmaf(a2.w, w3, bj))));
    float e3 = fmaf(a3.x, w0, fmaf(a3.y, w1, fmaf(a3.z, w2, fmaf(a3.w, w3, bj))));
    acc += fmaxf(h0 + e0, 0.f);
    acc += fmaxf(h1 + e1, 0.f);
    acc += fmaxf(h2 + e2, 0.f);
    acc += fmaxf(h3 + e3, 0.f);
  }
  for (; i < e; ++i){
    int sc = srcs[i];
    float4 a = ea4[i];
    float eav = fmaf(a.x, w0, fmaf(a.y, w1, fmaf(a.z, w2, fmaf(a.w, w3, bj))));
    acc += fmaxf(bf2f(hb[(size_t)sc * HD + j]) + eav, 0.f);
  }
  z[(size_t)n * HD + j] = f2bf(acc);
}

// ------- fused MLP (R12 structure; z-staging via global_load_lds width=16) -------
// t = relu(z@W1+b1) in LDS; z2 = t@W2+b2; LN+relu+residual.
// 512 thr, LDS = 64KB -> 2 blocks/CU. LDS dest is LINEAR (lane x 16B); the XOR
// swizzle is applied to the GLOBAL source chunk index (m173 pattern), so the
// phase-1 swizzled reads are unchanged.
__global__ __launch_bounds__(512, 4) void mlp_fused_kernel(
    const ushort_t* __restrict__ zin, const ushort_t* __restrict__ W1t,
    const float* __restrict__ b1, const ushort_t* __restrict__ W2t,
    const float* __restrict__ b2, const float* __restrict__ gamma,
    const float* __restrict__ beta, float* __restrict__ h,
    ushort_t* __restrict__ hb, int N){
  extern __shared__ char lds[];   // [0,32K): z tile; then [0,64K): t tile; [0,4K): stats
  int tid = threadIdx.x;
  int r0 = blockIdx.x * 128;
  // ---- stage z tile [128 node][128 k] bf16 via async global->LDS ----
  // linear LDS slot g*16 <- z[row][ (kg ^ (row&7)) * 8 .. +8 ]
  #pragma unroll
  for (int i = 0; i < 4; ++i){
    int g = i * 512 + tid;
    int row = g >> 4, kg = g & 15;
    int ar = min(r0 + row, N - 1);
    const ushort_t* gp = zin + (size_t)ar * 128 + (kg ^ (row & 7)) * 8;
    __builtin_amdgcn_global_load_lds((gas_t*)gp, (las_t*)(lds + g * 16), 16, 0, 0);
  }
  int w = tid >> 6, l = tid & 63;
  int lr = l & 15, lk = l >> 4;
  int wk = w >> 1, wn = w & 1;
  // prefetch phase-1 ks=0 weight fragments BEFORE the staging barrier
  bf16x8 aN[4];
  #pragma unroll
  for (int fm = 0; fm < 4; ++fm)
    aN[fm] = *(const bf16x8*)((const char*)W1t +
              (size_t)(wk * 64 + fm * 16 + lr) * 256 + lk * 16);
  __syncthreads();                                  // bar1: z staged (drains vmcnt)
  // ---- phase 1: wave grid wk(4) x wn(2); each wave 64 k2 x 64 node ----
  {
    f32x4 acc1[4][4] = {};
    #pragma unroll
    for (int ks = 0; ks < 4; ++ks){
      int kb = ks * 64 + lk * 16;                   // byte offset in 256B z-row
      bf16x8 aC[4];
      #pragma unroll
      for (int fm = 0; fm < 4; ++fm) aC[fm] = aN[fm];
      if (ks < 3){
        int kbn = (ks + 1) * 64 + lk * 16;
        #pragma unroll
        for (int fm = 0; fm < 4; ++fm)
          aN[fm] = *(const bf16x8*)((const char*)W1t +
                    (size_t)(wk * 64 + fm * 16 + lr) * 256 + kbn);
      }
      bf16x8 b[4];
      #pragma unroll
      for (int fn = 0; fn < 4; ++fn){
        int node = wn * 64 + fn * 16 + lr;
        b[fn] = *(const bf16x8*)(lds + node * 256 + (kb ^ ((node & 7) << 4)));
      }
      #pragma unroll
      for (int fm = 0; fm < 4; ++fm)
        #pragma unroll
        for (int fn = 0; fn < 4; ++fn)
          acc1[fm][fn] = mfma16(aC[fm], b[fn], acc1[fm][fn]);
    }
    __syncthreads();                                // bar2: z reads done, overwrite with t
    // bias + relu + write t[node][k2] bf16 (swizzled, row stride 512B)
    #pragma unroll
    for (int fm = 0; fm < 4; ++fm){
      f32x4 bv = *(const f32x4*)(b1 + wk * 64 + fm * 16 + lk * 4);
      int k2b = (wk * 64 + fm * 16 + lk * 4) * 2;   // byte offset in 512B t-row
      #pragma unroll
      for (int fn = 0; fn < 4; ++fn){
        int node = wn * 64 + fn * 16 + lr;
        ushort4 tv;
        tv.x = f2bf(fmaxf(acc1[fm][fn][0] + bv[0], 0.f));
        tv.y = f2bf(fmaxf(acc1[fm][fn][1] + bv[1], 0.f));
        tv.z = f2bf(fmaxf(acc1[fm][fn][2] + bv[2], 0.f));
        tv.w = f2bf(fmaxf(acc1[fm][fn][3] + bv[3], 0.f));
        *(ushort4*)(lds + node * 512 + (k2b ^ ((node & 7) << 4))) = tv;
      }
    }
  }
  // prefetch phase-2 ks=0 weight fragments BEFORE the t barrier
  int wd = w >> 1, wn2 = w & 1;
  bf16x8 a2N[2];
  #pragma unroll
  for (int fm = 0; fm < 2; ++fm)
    a2N[fm] = *(const bf16x8*)((const char*)W2t +
               (size_t)(wd * 32 + fm * 16 + lr) * 512 + lk * 16);
  __syncthreads();                                  // bar3: t fully written
  // ---- phase 2: wave grid wd(4) x wn2(2); each wave 32 d x 64 node ----
  f32x4 acc2[2][4] = {};
  #pragma unroll
  for (int ks = 0; ks < 8; ++ks){
    int kb = ks * 64 + lk * 16;                     // byte offset in 512B t-row
    bf16x8 a2C[2];
    #pragma unroll
    for (int fm = 0; fm < 2; ++fm) a2C[fm] = a2N[fm];
    if (ks < 7){
      int kbn = (ks + 1) * 64 + lk * 16;
      #pragma unroll
      for (int fm = 0; fm < 2; ++fm)
        a2N[fm] = *(const bf16x8*)((const char*)W2t +
                   (size_t)(wd * 32 + fm * 16 + lr) * 512 + kbn);
    }
    bf16x8 bt2[4];
    #pragma unroll
    for (int fn = 0; fn < 4; ++fn){
      int node = wn2 * 64 + fn * 16 + lr;
      bt2[fn] = *(const bf16x8*)(lds + node * 512 + (kb ^ ((node & 7) << 4)));
    }
    #pragma unroll
    for (int fm = 0; fm < 2; ++fm)
      #pragma unroll
      for (int fn = 0; fn < 4; ++fn)
        acc2[fm][fn] = mfma16(a2C[fm], bt2[fn], acc2[fm][fn]);
  }
  __syncthreads();                                  // bar4: t reads done, stat region free
  float* stat_s = (float*)lds;                      // [128 node][4 wd]
  float* stat_q = (float*)(lds + 2048);
  f32x4 b2v[2], gv[2], btv[2];
  #pragma unroll
  for (int fm = 0; fm < 2; ++fm){
    int db = wd * 32 + fm * 16 + lk * 4;
    b2v[fm] = *(const f32x4*)(b2 + db);
    gv[fm]  = *(const f32x4*)(gamma + db);
    btv[fm] = *(const f32x4*)(beta + db);
  }
  #pragma unroll
  for (int fn = 0; fn < 4; ++fn){
    float ss = 0.f, qq = 0.f;
    #pragma unroll
    for (int fm = 0; fm < 2; ++fm)
      #pragma unroll
      for (int r = 0; r < 4; ++r){
        float v = acc2[fm][fn][r] + b2v[fm][r];
        acc2[fm][fn][r] = v;
        ss += v; qq += v * v;
      }
    ss += __shfl_xor(ss, 16, 64); ss += __shfl_xor(ss, 32, 64);
    qq += __shfl_xor(qq, 16, 64); qq += __shfl_xor(qq, 32, 64);
    if (l < 16){
      int node = wn2 * 64 + fn * 16 + lr;
      stat_s[node * 4 + wd] = ss;
      stat_q[node * 4 + wd] = qq;
    }
  }
  __syncthreads();                                  // bar5: stats ready
  #pragma unroll
  for (int fn = 0; fn < 4; ++fn){
    int node = wn2 * 64 + fn * 16 + lr;
    int gn = r0 + node;
    float ss = stat_s[node * 4 + 0] + stat_s[node * 4 + 1] +
               stat_s[node * 4 + 2] + stat_s[node * 4 + 3];
    float qq = stat_q[node * 4 + 0] + stat_q[node * 4 + 1] +
               stat_q[node * 4 + 2] + stat_q[node * 4 + 3];
    float mean = ss * (1.f / 128.f);
    float rs = rsqrtf(qq * (1.f / 128.f) - mean * mean + 1e-5f);
    if (gn < N){
      #pragma unroll
      for (int fm = 0; fm < 2; ++fm){
        int db = wd * 32 + fm * 16 + lk * 4;
        f32x4 hold = *(const f32x4*)(h + (size_t)gn * HD + db);
        f32x4 ov;
        #pragma unroll
        for (int r = 0; r < 4; ++r)
          ov[r] = fmaxf((acc2[fm][fn][r] - mean) * rs * gv[fm][r] + btv[fm][r], 0.f) + hold[r];
        *(f32x4*)(h + (size_t)gn * HD + db) = ov;
        ushort4 hv;
        hv.x = f2bf(ov[0]); hv.y = f2bf(ov[1]); hv.z = f2bf(ov[2]); hv.w = f2bf(ov[3]);
        *(ushort4*)(hb + (size_t)gn * HD + db) = hv;
      }
    }
  }
}

// ---------------- pool (batch is sorted -> contiguous node ranges) ----------------
__global__ void pool_kernel(const float* __restrict__ h, const int* __restrict__ goff,
                            float* __restrict__ outp, int G){
  int g = blockIdx.x, j = threadIdx.x;
  int s = goff[g], e = goff[g + 1];
  float acc = 0.f;
  for (int i = s; i < e; ++i) acc += h[(size_t)i * HD + j];
  outp[(size_t)g * HD + j] = acc;
}

extern "C" void kernel_launch(void* const* d_in, const int* in_sizes, int n_in,
                              void* d_out, int out_size, void* d_ws, size_t ws_size,
                              hipStream_t stream){
  const float* x     = (const float*)d_in[0];
  const int*   ei    = (const int*)  d_in[1];
  const float* eattr = (const float*)d_in[2];
  const int*   batch = (const int*)  d_in[3];
  const float* Wn    = (const float*)d_in[4];
  const float* bn    = (const float*)d_in[5];
  const float* We    = (const float*)d_in[6];
  const float* be    = (const float*)d_in[7];
  const float* W1    = (const float*)d_in[8];
  const float* b1    = (const float*)d_in[9];
  const float* W2    = (const float*)d_in[10];
  const float* b2    = (const float*)d_in[11];
  const float* gamma = (const float*)d_in[12];
  const float* beta  = (const float*)d_in[13];
  float* outp = (float*)d_out;

  int N = in_sizes[3];
  int E = in_sizes[2] / 4;
  int G = out_size / HD;

  char* base = (char*)d_ws;
  size_t o = 0;
  auto alloc = [&](size_t bytes)->char*{
    char* r = base + o; o = (o + bytes + 255) & ~(size_t)255; return r;
  };
  float*    h    = (float*)   alloc((size_t)N * HD * 4);
  ushort_t* hb   = (ushort_t*)alloc((size_t)N * HD * 2);
  ushort_t* z    = (ushort_t*)alloc((size_t)N * HD * 2);
  ushort_t* W1t  = (ushort_t*)alloc((size_t)NL * 2 * HD * HD * 2);
  ushort_t* W2t  = (ushort_t*)alloc((size_t)NL * 2 * HD * HD * 2);
  int* deg    = (int*)alloc((size_t)N * 4);
  int* off    = (int*)alloc((size_t)(N + 1) * 4);
  int* goff   = (int*)alloc((size_t)(G + 1) * 4);
  int* cursor = (int*)alloc((size_t)N * 4);
  int* bsumN  = (int*)alloc(512 * 4);
  int* bofsN  = (int*)alloc(512 * 4);
  int* perm   = (int*)alloc((size_t)E * 4);
  int* srcs_s = (int*)alloc((size_t)E * 4);
  float4* ea4p= (float4*)alloc((size_t)E * 16);
  (void)ws_size; (void)n_in;

  const int* src = ei;
  const int* dst = ei + E;

  hipMemsetAsync(deg, 0, (size_t)N * 4, stream);

  hist_kernel<<<(E + 255) / 256, 256, 0, stream>>>(dst, deg, E);
  gbound_kernel<<<(N + 255) / 256, 256, 0, stream>>>(batch, goff, N, G);

  int BN = (N + SCAN_C - 1) / SCAN_C;
  scan_part<<<BN, 256, 0, stream>>>(deg, bsumN, N);
  scan_top<<<1, 256, 0, stream>>>(bsumN, bofsN, off + N, BN);
  scan_final<<<BN, 256, 0, stream>>>(deg, bofsN, off, cursor, N);

  scatter_kernel<<<(E + 255) / 256, 256, 0, stream>>>(dst, cursor, perm, E);
  permute_kernel<<<(E + 255) / 256, 256, 0, stream>>>(perm, src, (const float4*)eattr,
                                                      srcs_s, ea4p, E);
  wconv_kernel<<<(2 * NL * 32768) / 256, 256, 0, stream>>>(W1, W2, W1t, W2t);
  encoder_kernel<<<N, HD, 0, stream>>>(x, Wn, bn, h, hb, N);

  int mblocks = (N + 127) / 128;
  for (int l = 0; l < NL; ++l){
    agg_kernel<<<N, HD, 0, stream>>>(h, hb, off, srcs_s, ea4p, We, be, z, N);
    mlp_fused_kernel<<<mblocks, 512, 65536, stream>>>(
        z, W1t + (size_t)l * 2 * HD * HD, b1 + l * 2 * HD,
        W2t + (size_t)l * 2 * HD * HD, b2 + l * HD,
        gamma + l * HD, beta + l * HD, h, hb, N);
  }
  pool_kernel<<<G, HD, 0, stream>>>(h, goff, outp, G);
}